// Round 13
// baseline (22.985 us; speedup 1.0000x reference)
//
#include <hip/hip_runtime.h>
#include <float.h>

#define NB 8
#define NC 64
#define NQ 8
#define NK 256
#define NROWS 524288
#define TPB 256
#define RPB 1024                 // rows per vq_main block
#define NBLK2 512
#define BIT_OFF 1
#define REC_OFF (1 + NROWS*NQ)
#define NWV 16                   // x-intervals per channel
#define SLOT 96                  // list slots per interval

// unaligned-capable float4 (output base is +1 float => addr ≡ 4 mod 16)
typedef float f4u __attribute__((ext_vector_type(4), aligned(4)));

// ws layout (bytes), total 899072:
//  g_brk f64 [64][16][96] @ 0       (786432)
//  g_win u8  [64][16][96] @ 786432  ( 98304)
//  g_cnt s16 [64][16]     @ 884736  (  2048)
//  g_M   f64 [64][16]     @ 886784  (  8192)
//  part  f64 [512]        @ 894976  (  4096)
#define WS_BRK(ws)  ((double*)(ws))
#define WS_WIN(ws)  ((unsigned char*)((char*)(ws) + 786432))
#define WS_CNT(ws)  ((short*)((char*)(ws) + 884736))
#define WS_M(ws)    ((double*)((char*)(ws) + 886784))
#define WS_PART(ws) ((double*)((char*)(ws) + 894976))

// Cauchy quantiles tan(pi*(w/16 - 1/2)); index 0 unused as a start
__device__ __constant__ double c_tanq[17] = {
    0.0,
    -5.027339492125846, -2.414213562373095, -1.496605762665489, -1.0,
    -0.6681786379192989, -0.41421356237309503, -0.198912367379658, 0.0,
    0.198912367379658, 0.41421356237309503, 0.6681786379192989, 1.0,
    1.496605762665489, 2.414213562373095, 5.027339492125846, 0.0 };

// ---------------------------------------------------------------------------
// Kernel A (unchanged from R12, verified): 1024 blocks x 64 thr; block (c,w)
// walks the envelope over its x-interval with the verified step code.
// ---------------------------------------------------------------------------
__global__ __launch_bounds__(64) void vq_envelope(
    const float* __restrict__ w_pre,
    const float* __restrict__ b_pre,
    const float* __restrict__ codebook,
    double* __restrict__ g_brk,
    unsigned char* __restrict__ g_win,
    short* __restrict__ g_cnt,
    double* __restrict__ g_M)
{
    __shared__ double2 s_PS[NK];

    const int bid  = blockIdx.x;
    const int c    = bid >> 4;
    const int w    = bid & 15;
    const int lane = threadIdx.x;

    double wp[NQ], bp[NQ];
    #pragma unroll
    for (int q = 0; q < NQ; q++) {
        wp[q] = (double)w_pre[c*NQ + q];
        bp[q] = (double)b_pre[c*NQ + q];
    }

    double P[4], S[4];
    double r0 = 0.0, r1 = 0.0, r2 = 0.0, r3 = 0.0, r4 = 0.0;
    #pragma unroll
    for (int i = 0; i < 4; i++) {
        const int k = 4*lane + i;
        double c2 = 0.0, A = 0.0, Bv = 0.0;
        #pragma unroll
        for (int q = 0; q < NQ; q++) {
            const double cv = (double)codebook[k*NQ + q];
            c2 = fma(cv, cv, c2);
            A  = fma(wp[q], cv, A);
            Bv = fma(bp[q], cv, Bv);
        }
        P[i] = c2 - 2.0*Bv;
        S[i] = -2.0*A;
        s_PS[k] = make_double2(P[i], S[i]);
        r0 += P[i]; r1 += P[i]*P[i]; r2 += S[i]; r3 += S[i]*S[i]; r4 += P[i]*S[i];
    }
    __syncthreads();

    #pragma unroll
    for (int off = 32; off; off >>= 1) {
        r0 += __shfl_xor(r0, off, 64);
        r1 += __shfl_xor(r1, off, 64);
        r2 += __shfl_xor(r2, off, 64);
        r3 += __shfl_xor(r3, off, 64);
        r4 += __shfl_xor(r4, off, 64);
    }
    const double n  = 256.0;
    const double mP = r0/n, mS = r2/n;
    const double vP = fmax(r1/n - mP*mP, 0.0);
    const double vS = fmax(r3/n - mS*mS, 1e-300);
    const double cv = r4/n - mP*mS;
    const double m0 = -cv / vS;
    const double gm = sqrt(fmax(vP - cv*cv/vS, 0.0) / vS) + 1e-300;
    const double Ms  = fma(gm, c_tanq[w], m0);
    const double Mhi = (w == NWV-1) ? DBL_MAX : fma(gm, c_tanq[w+1], m0);
    if (lane == 0) g_M[c*NWV + w] = (w == 0) ? -DBL_MAX : Ms;

    int cur;
    if (w == 0) {
        double bs = S[0], bP = P[0];
        int bk = 4*lane;
        #pragma unroll
        for (int i = 1; i < 4; i++) {
            const int k = 4*lane + i;
            if (S[i] > bs || (S[i] == bs && (P[i] < bP || (P[i] == bP && k < bk)))) {
                bs = S[i]; bP = P[i]; bk = k;
            }
        }
        #pragma unroll
        for (int off = 32; off; off >>= 1) {
            double os = __shfl_xor(bs, off, 64);
            double oP = __shfl_xor(bP, off, 64);
            int    ok = __shfl_xor(bk, off, 64);
            if (os > bs || (os == bs && (oP < bP || (oP == bP && ok < bk)))) {
                bs = os; bP = oP; bk = ok;
            }
        }
        cur = bk;
    } else {
        double bd = fma(Ms, S[0], P[0]);
        int bk = 4*lane;
        #pragma unroll
        for (int i = 1; i < 4; i++) {
            const double d = fma(Ms, S[i], P[i]);
            const int k = 4*lane + i;
            if (d < bd || (d == bd && k < bk)) { bd = d; bk = k; }
        }
        #pragma unroll
        for (int off = 32; off; off >>= 1) {
            double od = __shfl_xor(bd, off, 64);
            int    ok = __shfl_xor(bk, off, 64);
            if (od < bd || (od == bd && ok < bk)) { bd = od; bk = ok; }
        }
        cur = bk;
    }

    const int gb = (c*NWV + w) * SLOT;
    if (lane == 0) g_win[gb] = (unsigned char)cur;
    int p = 1;
    bool trunc = false;

    while (true) {
        const double2 psi = s_PS[cur];
        const double Pi = psi.x, Si = psi.y;

        double cx = DBL_MAX, cs = 0.0;
        int cj = NK;
        #pragma unroll
        for (int i = 0; i < 4; i++) {
            const int k = 4*lane + i;
            if (S[i] < Si) {
                const double tt = (P[i] - Pi) / (Si - S[i]);
                if (tt < cx || (tt == cx && (S[i] < cs || (S[i] == cs && k < cj)))) {
                    cx = tt; cs = S[i]; cj = k;
                }
            }
        }
        #pragma unroll
        for (int off = 32; off; off >>= 1) {
            double ox = __shfl_xor(cx, off, 64);
            double os = __shfl_xor(cs, off, 64);
            int    oj = __shfl_xor(cj, off, 64);
            if (ox < cx || (ox == cx && (os < cs || (os == cs && oj < cj)))) {
                cx = ox; cs = os; cj = oj;
            }
        }
        if (cx >= Mhi) break;
        if (p >= SLOT) { trunc = true; break; }
        if (lane == 0) {
            g_brk[gb + p] = cx;
            g_win[gb + p] = (unsigned char)cj;
        }
        cur = cj;
        p++;
    }
    if (lane == 0) g_cnt[c*NWV + w] = trunc ? (short)-1 : (short)p;
}

// ---------------------------------------------------------------------------
// Kernel B: 512 blocks x 256 thr; thread handles 4 CONTIGUOUS rows tid*4+i.
// float4 x load (aligned), wide 16B stores per output plane (unaligned-safe),
// split points held in registers. Same j selection as R12 (bit-identical).
// ---------------------------------------------------------------------------
__global__ __launch_bounds__(TPB) void vq_main(
    const float* __restrict__ x,
    const float* __restrict__ w_pre,
    const float* __restrict__ b_pre,
    const float* __restrict__ codebook,
    const float* __restrict__ w_after,
    const float* __restrict__ b_after,
    const double* __restrict__ g_brk,
    const unsigned char* __restrict__ g_win,
    const short* __restrict__ g_cnt,
    const double* __restrict__ g_M,
    float* __restrict__ out,
    double* __restrict__ partial)
{
    __shared__ float  s_cb[NK][9];          // stride 9: conflict-light
    __shared__ float  s_R[NK];
    __shared__ double s_bg[NK][2];          // {beta, gamma} per code
    __shared__ double s_brk[NWV*SLOT];      // 12 KB
    __shared__ unsigned char s_win[NWV*SLOT];
    __shared__ short  s_cnt[NWV];
    __shared__ double s_M[NWV];
    __shared__ int    s_bad;
    __shared__ double s_part[TPB/64];

    const int tid = threadIdx.x;
    const int bc = blockIdx.x;
    const int b = bc >> 6;
    const int c = bc & 63;
    const int rowbase = bc * RPB;

    double wp[NQ], bp[NQ], wa[NQ];
    double sw2 = 0.0, swb = 0.0, sb2 = 0.0;
    #pragma unroll
    for (int q = 0; q < NQ; q++) {
        wp[q] = (double)w_pre[c*NQ + q];
        bp[q] = (double)b_pre[c*NQ + q];
        wa[q] = (double)w_after[c*NQ + q];
        sw2 = fma(wp[q], wp[q], sw2);
        swb = fma(wp[q], bp[q], swb);
        sb2 = fma(bp[q], bp[q], sb2);
    }
    const double ba = (double)b_after[c];
    const double alpha = sw2;

    if (tid == 0) s_bad = 0;

    // per-code payload (verified fma chains)
    {
        const float4* cb4 = (const float4*)(codebook + tid*NQ);
        const float4 c0 = cb4[0], c1 = cb4[1];
        float cf[NQ] = {c0.x, c0.y, c0.z, c0.w, c1.x, c1.y, c1.z, c1.w};
        double c2 = 0.0, A = 0.0, Bv = 0.0, R = ba;
        #pragma unroll
        for (int q = 0; q < NQ; q++) {
            s_cb[tid][q] = cf[q];
            const double cvv = (double)cf[q];
            c2 = fma(cvv, cvv, c2);
            A  = fma(wp[q], cvv, A);
            Bv = fma(bp[q], cvv, Bv);
            R  = fma(wa[q], cvv, R);
        }
        const double Pv = c2 - 2.0*Bv;
        const double Sv = -2.0*A;
        s_R[tid] = (float)R;
        s_bg[tid][0] = Sv + 2.0*swb;        // beta
        s_bg[tid][1] = Pv + sb2;            // gamma
    }
    #pragma unroll
    for (int it = 0; it < (NWV*SLOT)/TPB; it++) {
        const int idx = it*TPB + tid;
        const double v = g_brk[c*(NWV*SLOT) + idx];
        s_brk[idx] = ((idx % SLOT) == 0) ? -DBL_MAX : v;
        s_win[idx] = g_win[c*(NWV*SLOT) + idx];
    }
    if (tid < NWV) {
        const short cv = g_cnt[c*NWV + tid];
        s_cnt[tid] = cv;
        if (cv < 0) s_bad = 1;
        s_M[tid] = g_M[c*NWV + tid];
    }
    __syncthreads();
    const bool bad = (s_bad != 0);

    // split points in registers (1..15)
    double M[NWV];
    #pragma unroll
    for (int i = 1; i < NWV; i++) M[i] = s_M[i];

    const int bq0 = BIT_OFF + (b*512 + c*8)*1024;
    const int hw0 = tid * 4;
    const float4 xv4 = *(const float4*)(x + rowbase + hw0);
    double ktot = 0.0;
    int jj[4];

    #pragma unroll
    for (int i = 0; i < 4; i++) {
        const double xv = (double)((i==0)?xv4.x:(i==1)?xv4.y:(i==2)?xv4.z:xv4.w);

        int j;
        if (!bad) {
            int w = 0;
            #pragma unroll
            for (int k = 1; k < NWV; k++) w = (M[k] <= xv) ? k : w;
            const int base = w*SLOT;
            int lo = 0, hi = (int)s_cnt[w] - 1;
            while (lo < hi) {
                const int mid = (lo + hi + 1) >> 1;
                if (s_brk[base + mid] <= xv) lo = mid; else hi = mid - 1;
            }
            j = (int)s_win[base + lo];
        } else {
            double bd = DBL_MAX; j = 0;
            for (int k = 0; k < NK; k++) {
                const double d = fma(xv, s_bg[k][0], s_bg[k][1]);
                if (d < bd) { bd = d; j = k; }
            }
        }
        jj[i] = j;
        ktot += fma(xv, fma(xv, alpha, s_bg[j][0]), s_bg[j][1]);
    }

    // wide stores: one 16B store per output plane
    #pragma unroll
    for (int q = 0; q < NQ; q++) {
        f4u v = { s_cb[jj[0]][q], s_cb[jj[1]][q], s_cb[jj[2]][q], s_cb[jj[3]][q] };
        *(f4u*)(out + bq0 + q*1024 + hw0) = v;
    }
    {
        f4u v = { s_R[jj[0]], s_R[jj[1]], s_R[jj[2]], s_R[jj[3]] };
        *(f4u*)(out + REC_OFF + rowbase + hw0) = v;
    }

    #pragma unroll
    for (int off = 32; off; off >>= 1)
        ktot += __shfl_down(ktot, off, 64);
    if ((tid & 63) == 0) s_part[tid >> 6] = ktot;
    __syncthreads();
    if (tid == 0)
        partial[blockIdx.x] = s_part[0] + s_part[1] + s_part[2] + s_part[3];
}

__global__ __launch_bounds__(TPB) void vq_fin(
    const double* __restrict__ partial,
    float* __restrict__ out)
{
    double s = 0.0;
    for (int i = threadIdx.x; i < NBLK2; i += TPB) s += partial[i];
    #pragma unroll
    for (int off = 32; off; off >>= 1)
        s += __shfl_down(s, off, 64);
    __shared__ double sp[TPB/64];
    if ((threadIdx.x & 63) == 0) sp[threadIdx.x >> 6] = s;
    __syncthreads();
    if (threadIdx.x == 0) {
        double m = (sp[0] + sp[1] + sp[2] + sp[3]) / (double)(NROWS * NQ);
        out[0] = (float)(1.25 * m);
    }
}

extern "C" void kernel_launch(void* const* d_in, const int* in_sizes, int n_in,
                              void* d_out, int out_size, void* d_ws, size_t ws_size,
                              hipStream_t stream) {
    const float* x        = (const float*)d_in[0];
    const float* w_pre    = (const float*)d_in[1];
    const float* b_pre    = (const float*)d_in[2];
    const float* codebook = (const float*)d_in[3];
    const float* w_after  = (const float*)d_in[4];
    const float* b_after  = (const float*)d_in[5];
    float* out = (float*)d_out;

    vq_envelope<<<NC*NWV, 64, 0, stream>>>(w_pre, b_pre, codebook,
                                           WS_BRK(d_ws), WS_WIN(d_ws),
                                           WS_CNT(d_ws), WS_M(d_ws));
    vq_main<<<NBLK2, TPB, 0, stream>>>(x, w_pre, b_pre, codebook, w_after, b_after,
                                       WS_BRK(d_ws), WS_WIN(d_ws), WS_CNT(d_ws),
                                       WS_M(d_ws), out, WS_PART(d_ws));
    vq_fin<<<1, TPB, 0, stream>>>(WS_PART(d_ws), out);
}

// Round 14
// 22.837 us; speedup vs baseline: 1.0065x; 1.0065x over previous
//
#include <hip/hip_runtime.h>
#include <float.h>

#define NB 8
#define NC 64
#define NQ 8
#define NK 256
#define NROWS 524288
#define RPB 1024                 // rows per vq_main block
#define NBLK2 512
#define TPBM 512                 // vq_main threads (16 waves/CU at 2 blk/CU)
#define BIT_OFF 1
#define REC_OFF (1 + NROWS*NQ)
#define NWV 16                   // x-intervals per channel
#define SLOT 96                  // list slots per interval

// unaligned-capable vectors (output base is +1 float)
typedef float f2u __attribute__((ext_vector_type(2), aligned(4)));

// ws layout (bytes), total 899072:
//  g_brk f64 [64][16][96] @ 0       (786432)
//  g_win u8  [64][16][96] @ 786432  ( 98304)
//  g_cnt s16 [64][16]     @ 884736  (  2048)
//  g_M   f64 [64][16]     @ 886784  (  8192)
//  part  f64 [512]        @ 894976  (  4096)
#define WS_BRK(ws)  ((double*)(ws))
#define WS_WIN(ws)  ((unsigned char*)((char*)(ws) + 786432))
#define WS_CNT(ws)  ((short*)((char*)(ws) + 884736))
#define WS_M(ws)    ((double*)((char*)(ws) + 886784))
#define WS_PART(ws) ((double*)((char*)(ws) + 894976))

// Cauchy quantiles tan(pi*(w/16 - 1/2)); index 0 unused as a start
__device__ __constant__ double c_tanq[17] = {
    0.0,
    -5.027339492125846, -2.414213562373095, -1.496605762665489, -1.0,
    -0.6681786379192989, -0.41421356237309503, -0.198912367379658, 0.0,
    0.198912367379658, 0.41421356237309503, 0.6681786379192989, 1.0,
    1.496605762665489, 2.414213562373095, 5.027339492125846, 0.0 };

// ---------------------------------------------------------------------------
// Kernel A (unchanged, verified): 1024 blocks x 64 thr; block (c,w) walks the
// envelope over its x-interval with the verified step code.
// ---------------------------------------------------------------------------
__global__ __launch_bounds__(64) void vq_envelope(
    const float* __restrict__ w_pre,
    const float* __restrict__ b_pre,
    const float* __restrict__ codebook,
    double* __restrict__ g_brk,
    unsigned char* __restrict__ g_win,
    short* __restrict__ g_cnt,
    double* __restrict__ g_M)
{
    __shared__ double2 s_PS[NK];

    const int bid  = blockIdx.x;
    const int c    = bid >> 4;
    const int w    = bid & 15;
    const int lane = threadIdx.x;

    double wp[NQ], bp[NQ];
    #pragma unroll
    for (int q = 0; q < NQ; q++) {
        wp[q] = (double)w_pre[c*NQ + q];
        bp[q] = (double)b_pre[c*NQ + q];
    }

    double P[4], S[4];
    double r0 = 0.0, r1 = 0.0, r2 = 0.0, r3 = 0.0, r4 = 0.0;
    #pragma unroll
    for (int i = 0; i < 4; i++) {
        const int k = 4*lane + i;
        double c2 = 0.0, A = 0.0, Bv = 0.0;
        #pragma unroll
        for (int q = 0; q < NQ; q++) {
            const double cv = (double)codebook[k*NQ + q];
            c2 = fma(cv, cv, c2);
            A  = fma(wp[q], cv, A);
            Bv = fma(bp[q], cv, Bv);
        }
        P[i] = c2 - 2.0*Bv;
        S[i] = -2.0*A;
        s_PS[k] = make_double2(P[i], S[i]);
        r0 += P[i]; r1 += P[i]*P[i]; r2 += S[i]; r3 += S[i]*S[i]; r4 += P[i]*S[i];
    }
    __syncthreads();

    #pragma unroll
    for (int off = 32; off; off >>= 1) {
        r0 += __shfl_xor(r0, off, 64);
        r1 += __shfl_xor(r1, off, 64);
        r2 += __shfl_xor(r2, off, 64);
        r3 += __shfl_xor(r3, off, 64);
        r4 += __shfl_xor(r4, off, 64);
    }
    const double n  = 256.0;
    const double mP = r0/n, mS = r2/n;
    const double vP = fmax(r1/n - mP*mP, 0.0);
    const double vS = fmax(r3/n - mS*mS, 1e-300);
    const double cv = r4/n - mP*mS;
    const double m0 = -cv / vS;
    const double gm = sqrt(fmax(vP - cv*cv/vS, 0.0) / vS) + 1e-300;
    const double Ms  = fma(gm, c_tanq[w], m0);
    const double Mhi = (w == NWV-1) ? DBL_MAX : fma(gm, c_tanq[w+1], m0);
    if (lane == 0) g_M[c*NWV + w] = (w == 0) ? -DBL_MAX : Ms;

    int cur;
    if (w == 0) {
        double bs = S[0], bP = P[0];
        int bk = 4*lane;
        #pragma unroll
        for (int i = 1; i < 4; i++) {
            const int k = 4*lane + i;
            if (S[i] > bs || (S[i] == bs && (P[i] < bP || (P[i] == bP && k < bk)))) {
                bs = S[i]; bP = P[i]; bk = k;
            }
        }
        #pragma unroll
        for (int off = 32; off; off >>= 1) {
            double os = __shfl_xor(bs, off, 64);
            double oP = __shfl_xor(bP, off, 64);
            int    ok = __shfl_xor(bk, off, 64);
            if (os > bs || (os == bs && (oP < bP || (oP == bP && ok < bk)))) {
                bs = os; bP = oP; bk = ok;
            }
        }
        cur = bk;
    } else {
        double bd = fma(Ms, S[0], P[0]);
        int bk = 4*lane;
        #pragma unroll
        for (int i = 1; i < 4; i++) {
            const double d = fma(Ms, S[i], P[i]);
            const int k = 4*lane + i;
            if (d < bd || (d == bd && k < bk)) { bd = d; bk = k; }
        }
        #pragma unroll
        for (int off = 32; off; off >>= 1) {
            double od = __shfl_xor(bd, off, 64);
            int    ok = __shfl_xor(bk, off, 64);
            if (od < bd || (od == bd && ok < bk)) { bd = od; bk = ok; }
        }
        cur = bk;
    }

    const int gb = (c*NWV + w) * SLOT;
    if (lane == 0) g_win[gb] = (unsigned char)cur;
    int p = 1;
    bool trunc = false;

    while (true) {
        const double2 psi = s_PS[cur];
        const double Pi = psi.x, Si = psi.y;

        double cx = DBL_MAX, cs = 0.0;
        int cj = NK;
        #pragma unroll
        for (int i = 0; i < 4; i++) {
            const int k = 4*lane + i;
            if (S[i] < Si) {
                const double tt = (P[i] - Pi) / (Si - S[i]);
                if (tt < cx || (tt == cx && (S[i] < cs || (S[i] == cs && k < cj)))) {
                    cx = tt; cs = S[i]; cj = k;
                }
            }
        }
        #pragma unroll
        for (int off = 32; off; off >>= 1) {
            double ox = __shfl_xor(cx, off, 64);
            double os = __shfl_xor(cs, off, 64);
            int    oj = __shfl_xor(cj, off, 64);
            if (ox < cx || (ox == cx && (os < cs || (os == cs && oj < cj)))) {
                cx = ox; cs = os; cj = oj;
            }
        }
        if (cx >= Mhi) break;
        if (p >= SLOT) { trunc = true; break; }
        if (lane == 0) {
            g_brk[gb + p] = cx;
            g_win[gb + p] = (unsigned char)cj;
        }
        cur = cj;
        p++;
    }
    if (lane == 0) g_cnt[c*NWV + w] = trunc ? (short)-1 : (short)p;
}

// ---------------------------------------------------------------------------
// Kernel B: 512 blocks x 512 thr (16 waves/CU at 2 blocks/CU — 2x the latency
// hiding of R13); thread handles 2 contiguous rows. Same j selection as
// R12/R13 (bit-identical outputs).
// ---------------------------------------------------------------------------
__global__ __launch_bounds__(TPBM, 4) void vq_main(
    const float* __restrict__ x,
    const float* __restrict__ w_pre,
    const float* __restrict__ b_pre,
    const float* __restrict__ codebook,
    const float* __restrict__ w_after,
    const float* __restrict__ b_after,
    const double* __restrict__ g_brk,
    const unsigned char* __restrict__ g_win,
    const short* __restrict__ g_cnt,
    const double* __restrict__ g_M,
    float* __restrict__ out,
    double* __restrict__ partial)
{
    __shared__ float  s_cb[NK][9];          // stride 9: conflict-light
    __shared__ float  s_R[NK];
    __shared__ double s_bg[NK][2];          // {beta, gamma} per code
    __shared__ double s_brk[NWV*SLOT];      // 12 KB
    __shared__ unsigned char s_win[NWV*SLOT];
    __shared__ short  s_cnt[NWV];
    __shared__ double s_M[NWV];
    __shared__ int    s_bad;
    __shared__ double s_part[TPBM/64];

    const int tid = threadIdx.x;
    const int bc = blockIdx.x;
    const int b = bc >> 6;
    const int c = bc & 63;
    const int rowbase = bc * RPB;

    double wp[NQ], bp[NQ], wa[NQ];
    double sw2 = 0.0, swb = 0.0, sb2 = 0.0;
    #pragma unroll
    for (int q = 0; q < NQ; q++) {
        wp[q] = (double)w_pre[c*NQ + q];
        bp[q] = (double)b_pre[c*NQ + q];
        wa[q] = (double)w_after[c*NQ + q];
        sw2 = fma(wp[q], wp[q], sw2);
        swb = fma(wp[q], bp[q], swb);
        sb2 = fma(bp[q], bp[q], sb2);
    }
    const double ba = (double)b_after[c];
    const double alpha = sw2;

    if (tid == 0) s_bad = 0;

    // per-code payload (verified fma chains); first 256 threads
    if (tid < NK) {
        const float4* cb4 = (const float4*)(codebook + tid*NQ);
        const float4 c0 = cb4[0], c1 = cb4[1];
        float cf[NQ] = {c0.x, c0.y, c0.z, c0.w, c1.x, c1.y, c1.z, c1.w};
        double c2 = 0.0, A = 0.0, Bv = 0.0, R = ba;
        #pragma unroll
        for (int q = 0; q < NQ; q++) {
            s_cb[tid][q] = cf[q];
            const double cvv = (double)cf[q];
            c2 = fma(cvv, cvv, c2);
            A  = fma(wp[q], cvv, A);
            Bv = fma(bp[q], cvv, Bv);
            R  = fma(wa[q], cvv, R);
        }
        const double Pv = c2 - 2.0*Bv;
        const double Sv = -2.0*A;
        s_R[tid] = (float)R;
        s_bg[tid][0] = Sv + 2.0*swb;        // beta
        s_bg[tid][1] = Pv + sb2;            // gamma
    }
    #pragma unroll
    for (int it = 0; it < (NWV*SLOT)/TPBM; it++) {   // 3 iterations
        const int idx = it*TPBM + tid;
        const double v = g_brk[c*(NWV*SLOT) + idx];
        s_brk[idx] = ((idx % SLOT) == 0) ? -DBL_MAX : v;
        s_win[idx] = g_win[c*(NWV*SLOT) + idx];
    }
    if (tid < NWV) {
        const short cv = g_cnt[c*NWV + tid];
        s_cnt[tid] = cv;
        if (cv < 0) s_bad = 1;
        s_M[tid] = g_M[c*NWV + tid];
    }
    __syncthreads();
    const bool bad = (s_bad != 0);

    const int bq0 = BIT_OFF + (b*512 + c*8)*1024;
    const int hw0 = tid * 2;
    const float2 xv2 = *(const float2*)(x + rowbase + hw0);
    double ktot = 0.0;
    int jj[2];

    #pragma unroll
    for (int i = 0; i < 2; i++) {
        const double xv = (double)((i == 0) ? xv2.x : xv2.y);

        int j;
        if (!bad) {
            int w = 0;
            #pragma unroll
            for (int k = 1; k < NWV; k++) w = (s_M[k] <= xv) ? k : w;
            const int base = w*SLOT;
            int lo = 0, hi = (int)s_cnt[w] - 1;
            while (lo < hi) {
                const int mid = (lo + hi + 1) >> 1;
                if (s_brk[base + mid] <= xv) lo = mid; else hi = mid - 1;
            }
            j = (int)s_win[base + lo];
        } else {
            double bd = DBL_MAX; j = 0;
            for (int k = 0; k < NK; k++) {
                const double d = fma(xv, s_bg[k][0], s_bg[k][1]);
                if (d < bd) { bd = d; j = k; }
            }
        }
        jj[i] = j;
        ktot += fma(xv, fma(xv, alpha, s_bg[j][0]), s_bg[j][1]);
    }

    // one 8B store per output plane
    #pragma unroll
    for (int q = 0; q < NQ; q++) {
        f2u v = { s_cb[jj[0]][q], s_cb[jj[1]][q] };
        *(f2u*)(out + bq0 + q*1024 + hw0) = v;
    }
    {
        f2u v = { s_R[jj[0]], s_R[jj[1]] };
        *(f2u*)(out + REC_OFF + rowbase + hw0) = v;
    }

    #pragma unroll
    for (int off = 32; off; off >>= 1)
        ktot += __shfl_down(ktot, off, 64);
    if ((tid & 63) == 0) s_part[tid >> 6] = ktot;
    __syncthreads();
    if (tid == 0) {
        double s = 0.0;
        #pragma unroll
        for (int i = 0; i < TPBM/64; i++) s += s_part[i];
        partial[blockIdx.x] = s;
    }
}

__global__ __launch_bounds__(256) void vq_fin(
    const double* __restrict__ partial,
    float* __restrict__ out)
{
    double s = 0.0;
    for (int i = threadIdx.x; i < NBLK2; i += 256) s += partial[i];
    #pragma unroll
    for (int off = 32; off; off >>= 1)
        s += __shfl_down(s, off, 64);
    __shared__ double sp[4];
    if ((threadIdx.x & 63) == 0) sp[threadIdx.x >> 6] = s;
    __syncthreads();
    if (threadIdx.x == 0) {
        double m = (sp[0] + sp[1] + sp[2] + sp[3]) / (double)(NROWS * NQ);
        out[0] = (float)(1.25 * m);
    }
}

extern "C" void kernel_launch(void* const* d_in, const int* in_sizes, int n_in,
                              void* d_out, int out_size, void* d_ws, size_t ws_size,
                              hipStream_t stream) {
    const float* x        = (const float*)d_in[0];
    const float* w_pre    = (const float*)d_in[1];
    const float* b_pre    = (const float*)d_in[2];
    const float* codebook = (const float*)d_in[3];
    const float* w_after  = (const float*)d_in[4];
    const float* b_after  = (const float*)d_in[5];
    float* out = (float*)d_out;

    vq_envelope<<<NC*NWV, 64, 0, stream>>>(w_pre, b_pre, codebook,
                                           WS_BRK(d_ws), WS_WIN(d_ws),
                                           WS_CNT(d_ws), WS_M(d_ws));
    vq_main<<<NBLK2, TPBM, 0, stream>>>(x, w_pre, b_pre, codebook, w_after, b_after,
                                        WS_BRK(d_ws), WS_WIN(d_ws), WS_CNT(d_ws),
                                        WS_M(d_ws), out, WS_PART(d_ws));
    vq_fin<<<1, 256, 0, stream>>>(WS_PART(d_ws), out);
}